// Round 8
// baseline (60038.507 us; speedup 1.0000x reference)
//
#include <hip/hip_runtime.h>
#include <stdint.h>

// Decoder_71880572665909 : GRU scan (T=511) + 2 x (causal self-attn + cross-attn + MLP) + linear head
// B=64, S=512, HID=1024, POSE=96, L=2.
// Numerics architecture (round-8):
//   - H, X carried in exact f32 (the 511-step additive chains must not re-round).
//   - All GEMMs feeding the softmax-score path run triple-bf16 (hi/mid/lo, 2^-27 operands)
//     with 6 MFMA products (all i+j<=2); direct paths (V, P, head) run pair/X3.
//   - GRU consumes rolling triple views of the current h/x rows; phase 2 splits f32->triple per chunk.

typedef __attribute__((ext_vector_type(8))) short short8;
typedef __attribute__((ext_vector_type(4))) float f32x4;

__device__ __forceinline__ uint16_t f2bf(float f) {
  uint32_t u = __float_as_uint(f);
  uint32_t r = u + 0x7FFFu + ((u >> 16) & 1u);
  return (uint16_t)(r >> 16);
}
__device__ __forceinline__ float bf2f(uint16_t h) {
  return __uint_as_float(((uint32_t)h) << 16);
}
__device__ __forceinline__ float sigm(float x) { return 1.f / (1.f + __expf(-x)); }
__device__ __forceinline__ float tanh_(float x) { return 2.f / (1.f + __expf(-2.f * x)) - 1.f; }
__device__ __forceinline__ short8 ld8(const uint16_t* p) { return *(const short8*)p; }

__device__ __forceinline__ void stage16(const void* g, void* lds_base_uniform) {
  __builtin_amdgcn_global_load_lds((const __attribute__((address_space(1))) void*)g,
                                   (__attribute__((address_space(3))) void*)lds_base_uniform, 16, 0, 0);
}
__device__ __forceinline__ void tri_store(uint16_t* p, int o0, int o1, int o2, float v) {
  uint16_t hi = f2bf(v);
  float r = v - bf2f(hi);
  uint16_t mid = f2bf(r);
  p[o0] = hi; p[o1] = mid; p[o2] = f2bf(r - bf2f(mid));
}

// ---------------------------------------------------------------- prep / utility kernels

__global__ __launch_bounds__(256) void k_fill(float* __restrict__ o, int n, float v) {
  int i = blockIdx.x * 256 + threadIdx.x;
  if (i < n) o[i] = v;
}

__global__ __launch_bounds__(256) void k_cp4(const float4* __restrict__ s, float4* __restrict__ d, int n4) {
  int i = blockIdx.x * 256 + threadIdx.x;
  if (i < n4) d[i] = s[i];
}

// f32 [rows][K] -> triple bf16 [rows][3K] (hi|mid|lo)
__global__ __launch_bounds__(256) void k_split3(const float* __restrict__ s, uint16_t* __restrict__ d,
                                                int n, int K) {
  int id = blockIdx.x * 256 + threadIdx.x;
  if (id >= n) return;
  int row = id / K, k = id % K;
  tri_store(d, row * 3 * K + k, row * 3 * K + K + k, row * 3 * K + 2 * K + k, s[id]);
}

// f32 W [N][K] -> pair [Npad][2K]
__global__ __launch_bounds__(256) void k_fsplit(const float* __restrict__ s, uint16_t* __restrict__ d,
                                                int N, int K, int Npad) {
  int id = blockIdx.x * 256 + threadIdx.x;
  if (id >= Npad * K) return;
  int n = id / K, k = id % K;
  float w = (n < N) ? s[(long long)n * K + k] : 0.f;
  uint16_t hi = f2bf(w);
  d[(long long)n * 2 * K + k] = hi;
  d[(long long)n * 2 * K + K + k] = f2bf(w - bf2f(hi));
}

// f32 W [N][K] -> triple [Npad][3K]
__global__ __launch_bounds__(256) void k_wsplit3(const float* __restrict__ s, uint16_t* __restrict__ d,
                                                 int N, int K, int Npad) {
  int id = blockIdx.x * 256 + threadIdx.x;
  if (id >= Npad * K) return;
  int n = id / K, k = id % K;
  float w = (n < N) ? s[(long long)n * K + k] : 0.f;
  tri_store(d, (long long)n * 3 * K + k, (long long)n * 3 * K + K + k, (long long)n * 3 * K + 2 * K + k, w);
}

// x_{-1} = x0 - h0 @ tp_W^T - tp_b  (triple out; feeds step-0 gi)
__global__ __launch_bounds__(256) void k_xm1(const float* __restrict__ h, const float* __restrict__ gt,
                                             const float* __restrict__ tp_W, const float* __restrict__ tp_b,
                                             uint16_t* __restrict__ Xm1) {
  int id = blockIdx.x * 256 + threadIdx.x;
  if (id >= 64 * 96) return;
  int b = id / 96, c = id % 96;
  float s = gt[(long long)b * 512 * 96 + c] - tp_b[c];
  const float* hr = &h[(long long)b * 1024];
  const float* wr = &tp_W[(long long)c * 1024];
  for (int k = 0; k < 1024; k++) s -= hr[k] * wr[k];
  tri_store(Xm1, b * 288 + c, b * 288 + 96 + c, b * 288 + 192 + c, s);
}

// gates pack: K=1120 x N=6144 fragment order [384 tiles][35 ks][64][8], triple planes
__global__ __launch_bounds__(256) void k_pack(const float* __restrict__ W_hh, const float* __restrict__ W_ih,
                                              const float* __restrict__ tp_W,
                                              uint16_t* __restrict__ B0, uint16_t* __restrict__ B1,
                                              uint16_t* __restrict__ B2) {
  int id = blockIdx.x * 256 + threadIdx.x;
  if (id >= 384 * 35 * 64) return;
  int tile = id / 2240, rem = id % 2240;
  int ks = rem >> 6, l = rem & 63;
  int n = tile * 16 + (l & 15);
  int kb = ks * 32 + (l >> 4) * 8;
  short8 v0, v1, v2;
#pragma unroll
  for (int i = 0; i < 8; i++) {
    int k = kb + i;
    float m = 0.f;
    if (n < 3072) {
      m = (k < 1024) ? W_hh[(long long)n * 1024 + k] : 0.f;
    } else {
      int j = n - 3072;
      if (k < 1024) {
        float s = 0.f;
        for (int q = 0; q < 96; q++) s += tp_W[q * 1024 + k] * W_ih[(long long)j * 96 + q];
        m = s;
      } else {
        m = W_ih[(long long)j * 96 + (k - 1024)];
      }
    }
    uint16_t hi = f2bf(m);
    float r = m - bf2f(hi);
    uint16_t mid = f2bf(r);
    v0[i] = (short)hi; v1[i] = (short)mid; v2[i] = (short)f2bf(r - bf2f(mid));
  }
  *(short8*)&B0[(long long)id * 8] = v0;
  *(short8*)&B1[(long long)id * 8] = v1;
  *(short8*)&B2[(long long)id * 8] = v2;
}

// x-update pack: tp_W [6 tiles][32 ks][64][8], triple planes (plane stride 98304 u16)
__global__ __launch_bounds__(256) void k_packx(const float* __restrict__ tp_W, uint16_t* __restrict__ Bx) {
  int id = blockIdx.x * 256 + threadIdx.x;
  if (id >= 6 * 32 * 64) return;
  int tile = id / 2048, rem = id % 2048;
  int ks = rem >> 6, l = rem & 63;
  int c = tile * 16 + (l & 15);
  int lg = l >> 4;
  short8 v0, v1, v2;
#pragma unroll
  for (int i = 0; i < 8; i++) {
    int k = ks * 32 + lg * 8 + i;
    float w = tp_W[(long long)c * 1024 + k];
    uint16_t hi = f2bf(w);
    float r = w - bf2f(hi);
    uint16_t mid = f2bf(r);
    v0[i] = (short)hi; v1[i] = (short)mid; v2[i] = (short)f2bf(r - bf2f(mid));
  }
  *(short8*)&Bx[(long long)id * 8] = v0;
  *(short8*)&Bx[98304 + (long long)id * 8] = v1;
  *(short8*)&Bx[196608 + (long long)id * 8] = v2;
}

__global__ __launch_bounds__(256) void k_c6(const float* __restrict__ b_ih, const float* __restrict__ b_hh,
                                            const float* __restrict__ W_ih, const float* __restrict__ tp_b,
                                            float* __restrict__ c6m) {
  int n = blockIdx.x * 256 + threadIdx.x;
  if (n >= 6240) return;
  float m;
  if (n < 3072) { m = b_hh[n]; }
  else if (n < 6144) {
    int j = n - 3072;
    float s = 0.f;
    for (int q = 0; q < 96; q++) s += W_ih[(long long)j * 96 + q] * tp_b[q];
    m = b_ih[j] + s;
  } else { m = tp_b[n - 6144]; }
  c6m[n] = m;
}

__global__ __launch_bounds__(256) void k_init(const float* __restrict__ h, const float* __restrict__ gt,
                                              float* Hf, uint16_t* Hr, float* Xf, uint16_t* Xr) {
  int id = blockIdx.x * 256 + threadIdx.x;
  if (id < 65536) {
    int b = id >> 10, d = id & 1023;
    float v = h[id];
    Hf[((long long)b * 512) * 1024 + d] = v;
    tri_store(Hr, b * 3072 + d, b * 3072 + 1024 + d, b * 3072 + 2048 + d, v);
  } else {
    int r2 = id - 65536;
    if (r2 < 6144) {
      int b = r2 / 96, c = r2 % 96;
      float v = gt[(long long)b * 512 * 96 + c];
      Xf[((long long)b * 512) * 96 + c] = v;
      tri_store(Xr, b * 288 + c, b * 288 + 96 + c, b * 288 + 192 + c, v);
    }
  }
}

// ---------------------------------------------------------------- GRU step
// A operands read rolling triple buffers: Hcur [64][3072], Xg [64][288].
__device__ __forceinline__ void gA(short8* a, int word, int ks, const uint16_t* Hcur, const uint16_t* Xg,
                                   int lr, int lg) {
  if (ks < 32) {
    int k0 = word * 1024 + ks * 32 + lg * 8;
#pragma unroll
    for (int rt = 0; rt < 4; rt++)
      a[rt] = ld8(&Hcur[(rt * 16 + lr) * 3072 + k0]);
  } else {
    int k0 = word * 96 + (ks - 32) * 32 + lg * 8;
#pragma unroll
    for (int rt = 0; rt < 4; rt++)
      a[rt] = ld8(&Xg[(rt * 16 + lr) * 288 + k0]);
  }
}

__global__ __launch_bounds__(512) void k_gru(const uint16_t* __restrict__ B0, const uint16_t* __restrict__ B1,
                                             const uint16_t* __restrict__ B2, const uint16_t* __restrict__ Bx,
                                             const float* __restrict__ c6,
                                             float* Hf, uint16_t* Hr, float* Xf, uint16_t* Xr,
                                             const uint16_t* __restrict__ Xg,
                                             int p, int do_g, int do_x) {
  int tid = threadIdx.x, w = tid >> 6, l = tid & 63, lr = l & 15, lg = l >> 4;
  int blk = blockIdx.x;
  const uint16_t* Hcur = Hr + (p & 1) * 196608;
  uint16_t* Hnxt = Hr + ((p + 1) & 1) * 196608;
  uint16_t* Xw = Xr + (p & 1) * 18432;
  __shared__ float lds[64 * 192];

  if (blk == 32) {  // x-update: x_p = x_{p-1} + h_p @ tpW^T + tp_b ; 6 waves, 16 cols each, X6
    if (!do_x || w >= 6) return;
    f32x4 ac[4] = {};
    for (int ks = 0; ks < 32; ks++) {
      short8 a0[4], a1[4], a2[4];
      int k0 = ks * 32 + lg * 8;
#pragma unroll
      for (int rt = 0; rt < 4; rt++) {
        int hb = (rt * 16 + lr) * 3072;
        a0[rt] = ld8(&Hcur[hb + k0]);
        a1[rt] = ld8(&Hcur[hb + 1024 + k0]);
        a2[rt] = ld8(&Hcur[hb + 2048 + k0]);
      }
      long long bo = (((long long)w * 32 + ks) * 64 + l) * 8;
      short8 b0 = ld8(&Bx[bo]);
      short8 b1 = ld8(&Bx[98304 + bo]);
      short8 b2 = ld8(&Bx[196608 + bo]);
#pragma unroll
      for (int rt = 0; rt < 4; rt++) {
        ac[rt] = __builtin_amdgcn_mfma_f32_16x16x32_bf16(a0[rt], b0, ac[rt], 0, 0, 0);
        ac[rt] = __builtin_amdgcn_mfma_f32_16x16x32_bf16(a0[rt], b1, ac[rt], 0, 0, 0);
        ac[rt] = __builtin_amdgcn_mfma_f32_16x16x32_bf16(a1[rt], b0, ac[rt], 0, 0, 0);
        ac[rt] = __builtin_amdgcn_mfma_f32_16x16x32_bf16(a1[rt], b1, ac[rt], 0, 0, 0);
        ac[rt] = __builtin_amdgcn_mfma_f32_16x16x32_bf16(a0[rt], b2, ac[rt], 0, 0, 0);
        ac[rt] = __builtin_amdgcn_mfma_f32_16x16x32_bf16(a2[rt], b0, ac[rt], 0, 0, 0);
      }
    }
    int c = w * 16 + lr;
    float cb = c6[6144 + c];
#pragma unroll
    for (int rt = 0; rt < 4; rt++) {
#pragma unroll
      for (int rg = 0; rg < 4; rg++) {
        int b = rt * 16 + 4 * lg + rg;
        float xold = Xf[((long long)b * 512 + p - 1) * 96 + c];   // exact f32 chain
        float v = ac[rt][rg] + cb + xold;
        Xf[((long long)b * 512 + p) * 96 + c] = v;
        tri_store(Xw, b * 288 + c, b * 288 + 96 + c, b * 288 + 192 + c, v);
      }
    }
    return;
  }

  if (!do_g) return;
  // gates: hidden slice [blk*32,+32). 6 strips x 32 cols; 8 waves split K in halves. X6.
  int half = w >> 2, ws = w & 3;
  int ks0 = half ? 18 : 0, ks1 = half ? 35 : 18;
  int tiles[3], igs[3];
#pragma unroll
  for (int t = 0; t < 3; t++) {
    int ig = ws * 3 + t;
    igs[t] = ig;
    tiles[t] = 64 * (ig >> 1) + blk * 2 + (ig & 1);
  }
  f32x4 acc[3][4] = {};
  for (int ks = ks0; ks < ks1; ks++) {
    short8 a0[4], a1[4], a2[4];
    gA(a0, 0, ks, Hcur, Xg, lr, lg);
    gA(a1, 1, ks, Hcur, Xg, lr, lg);
    gA(a2, 2, ks, Hcur, Xg, lr, lg);
#pragma unroll
    for (int t = 0; t < 3; t++) {
      long long bo = (((long long)tiles[t] * 35 + ks) * 64 + l) * 8;
      short8 b0 = ld8(&B0[bo]);
      short8 b1 = ld8(&B1[bo]);
      short8 b2 = ld8(&B2[bo]);
#pragma unroll
      for (int rt = 0; rt < 4; rt++) {
        acc[t][rt] = __builtin_amdgcn_mfma_f32_16x16x32_bf16(a0[rt], b0, acc[t][rt], 0, 0, 0);
        acc[t][rt] = __builtin_amdgcn_mfma_f32_16x16x32_bf16(a0[rt], b1, acc[t][rt], 0, 0, 0);
        acc[t][rt] = __builtin_amdgcn_mfma_f32_16x16x32_bf16(a1[rt], b0, acc[t][rt], 0, 0, 0);
        acc[t][rt] = __builtin_amdgcn_mfma_f32_16x16x32_bf16(a1[rt], b1, acc[t][rt], 0, 0, 0);
        acc[t][rt] = __builtin_amdgcn_mfma_f32_16x16x32_bf16(a0[rt], b2, acc[t][rt], 0, 0, 0);
        acc[t][rt] = __builtin_amdgcn_mfma_f32_16x16x32_bf16(a2[rt], b0, acc[t][rt], 0, 0, 0);
      }
    }
  }
  if (half == 0) {
#pragma unroll
    for (int t = 0; t < 3; t++) {
      float cb = c6[tiles[t] * 16 + lr];
#pragma unroll
      for (int rt = 0; rt < 4; rt++)
#pragma unroll
        for (int rg = 0; rg < 4; rg++)
          lds[(rt * 16 + 4 * lg + rg) * 192 + igs[t] * 16 + lr] = acc[t][rt][rg] + cb;
    }
  }
  __syncthreads();
  if (half == 1) {
#pragma unroll
    for (int t = 0; t < 3; t++)
#pragma unroll
      for (int rt = 0; rt < 4; rt++)
#pragma unroll
        for (int rg = 0; rg < 4; rg++)
          lds[(rt * 16 + 4 * lg + rg) * 192 + igs[t] * 16 + lr] += acc[t][rt][rg];
  }
  __syncthreads();
  int b = tid & 63, g = tid >> 6;
  const float* row = &lds[b * 192];
#pragma unroll
  for (int q = 0; q < 4; q++) {
    int jj = g * 4 + q, j = blk * 32 + jj;
    float hr = row[jj], hz = row[32 + jj], hnn = row[64 + jj];
    float ir = row[96 + jj], iz = row[128 + jj], inn = row[160 + jj];
    float hp = Hf[((long long)b * 512 + p) * 1024 + j];              // exact f32 carry
    float r = sigm(ir + hr), z = sigm(iz + hz);
    float nn = tanh_(inn + r * hnn);
    float hv = (1.f - z) * nn + z * hp;
    Hf[((long long)b * 512 + p + 1) * 1024 + j] = hv;
    tri_store(Hnxt, b * 3072 + j, b * 3072 + 1024 + j, b * 3072 + 2048 + j, hv);
  }
}

// ---------------------------------------------------------------- generic multi-word GEMM
// A row-major [M][lda], words at w*koffA. B = B^T row-major [N][ldb], words at w*koffB.
// Accumulates all products a_i * b_j with i+j <= CUT.
template <int WF32, int WTRIP, int BIAS, int RESIDF, int LEAKY, int SCALE, int VLAY,
          int AW, int BW, int CUT>
__global__ __launch_bounds__(256) void k_gemmX(const uint16_t* __restrict__ A, int lda, long long bsA, int koffA,
                                               const uint16_t* __restrict__ B, int ldb, long long bsB, int koffB,
                                               float* __restrict__ C, int ldc, long long bsC,
                                               uint16_t* __restrict__ Cb, int ldcb, long long bsCb, int pairoff,
                                               const float* __restrict__ bias, float scale, int nk, int Nvalid) {
  int tid = threadIdx.x, w = tid >> 6, l = tid & 63, lr = l & 15, lg = l >> 4;
  long long bz = blockIdx.z;
  int brow = blockIdx.x * 128, bcol = blockIdx.y * 128;
  const uint16_t* Ab = A + bz * bsA;
  const uint16_t* Bb = B + bz * bsB;
  __shared__ uint16_t sm[(AW + BW) * 4096];
  char* L = (char*)sm;
  f32x4 acc[4][4] = {};
  int wr = (w >> 1) * 64, wc = (w & 1) * 64;
  int srow = tid >> 2, skoff = (tid & 3) * 8;
  for (int ks = 0; ks < nk; ks++) {
    __syncthreads();
    int k0 = ks * 32 + skoff;
#pragma unroll
    for (int aw = 0; aw < AW; aw++) {
      stage16(Ab + (long long)(brow + srow) * lda + aw * koffA + k0,      L + aw * 8192 + w * 1024);
      stage16(Ab + (long long)(brow + 64 + srow) * lda + aw * koffA + k0, L + aw * 8192 + 4096 + w * 1024);
    }
#pragma unroll
    for (int bw = 0; bw < BW; bw++) {
      stage16(Bb + (long long)(bcol + srow) * ldb + bw * koffB + k0,      L + (AW + bw) * 8192 + w * 1024);
      stage16(Bb + (long long)(bcol + 64 + srow) * ldb + bw * koffB + k0, L + (AW + bw) * 8192 + 4096 + w * 1024);
    }
    __syncthreads();
    short8 af[AW][4], bf[BW][4];
#pragma unroll
    for (int aw = 0; aw < AW; aw++)
#pragma unroll
      for (int mi = 0; mi < 4; mi++)
        af[aw][mi] = *(short8*)(L + aw * 8192 + ((wr + mi * 16 + lr) * 32 + lg * 8) * 2);
#pragma unroll
    for (int bw = 0; bw < BW; bw++)
#pragma unroll
      for (int ni = 0; ni < 4; ni++)
        bf[bw][ni] = *(short8*)(L + (AW + bw) * 8192 + ((wc + ni * 16 + lr) * 32 + lg * 8) * 2);
#pragma unroll
    for (int mi = 0; mi < 4; mi++)
#pragma unroll
      for (int ni = 0; ni < 4; ni++)
#pragma unroll
        for (int iw = 0; iw < AW; iw++)
#pragma unroll
          for (int jw = 0; jw < BW; jw++)
            if (iw + jw <= CUT)
              acc[mi][ni] = __builtin_amdgcn_mfma_f32_16x16x32_bf16(af[iw][mi], bf[jw][ni], acc[mi][ni], 0, 0, 0);
  }
#pragma unroll
  for (int mi = 0; mi < 4; mi++) {
#pragma unroll
    for (int ni = 0; ni < 4; ni++) {
      int row0 = brow + wr + mi * 16 + 4 * lg;
      int col = bcol + wc + ni * 16 + lr;
      if (col < Nvalid) {
#pragma unroll
        for (int rg = 0; rg < 4; rg++) {
          float v = acc[mi][ni][rg];
          if (SCALE) v *= scale;
          if (BIAS == 1) v += bias[col];
          if (BIAS == 2) v += bias[row0 + rg];
          if (RESIDF) {
            long long ci = bz * bsC + (long long)(row0 + rg) * ldc + col;
            v += C[ci];
            C[ci] = v;
          }
          if (LEAKY) v = (v > 0.f) ? v : 0.01f * v;
          if (WF32) C[bz * bsC + (long long)(row0 + rg) * ldc + col] = v;
          if (WTRIP) {
            long long cbi = bz * bsCb + (long long)(row0 + rg) * ldcb + col;
            tri_store(Cb, cbi, cbi + pairoff, cbi + 2 * pairoff, v);
          }
          if (VLAY) {  // V^T pair layout per chunk-batch: [bz2][d 1024][hi 512 | lo 512]
            int bz2 = col >> 9, t = col & 511;
            long long vi = (long long)bz2 * 1048576 + (long long)(row0 + rg) * 1024 + t;
            uint16_t hi = f2bf(v);
            Cb[vi] = hi; Cb[vi + 512] = f2bf(v - bf2f(hi));
          }
        }
      }
    }
  }
}

// ---------------------------------------------------------------- softmax (rows of 512), P pair overlays scr
__global__ __launch_bounds__(256) void k_softmax(float* __restrict__ sc, int causal) {
  int r = blockIdx.x * 4 + (threadIdx.x >> 6);
  int l = threadIdx.x & 63;
  int s = r & 511;
  long long base = (long long)r * 512;
  int t0 = l * 8;
  float4 p0 = *(const float4*)&sc[base + t0];
  float4 p1 = *(const float4*)&sc[base + t0 + 4];
  float v[8] = {p0.x, p0.y, p0.z, p0.w, p1.x, p1.y, p1.z, p1.w};
  float m = -3.0e38f;
#pragma unroll
  for (int i = 0; i < 8; i++) {
    bool ok = (!causal) || (t0 + i <= s);
    if (ok) m = fmaxf(m, v[i]);
  }
#pragma unroll
  for (int o = 32; o > 0; o >>= 1) m = fmaxf(m, __shfl_xor(m, o));
  float e[8];
  float sum = 0.f;
#pragma unroll
  for (int i = 0; i < 8; i++) {
    bool ok = (!causal) || (t0 + i <= s);
    e[i] = ok ? __expf(v[i] - m) : 0.f;
    sum += e[i];
  }
#pragma unroll
  for (int o = 32; o > 0; o >>= 1) sum += __shfl_xor(sum, o);
  float inv = 1.f / sum;
  short8 oh, ol;
#pragma unroll
  for (int i = 0; i < 8; i++) {
    float p = e[i] * inv;
    uint16_t hi = f2bf(p);
    oh[i] = hi; ol[i] = (short)f2bf(p - bf2f(hi));
  }
  // overlay: P row occupies the same 2048 bytes as the score row (single wave per row: all
  // lanes' loads above complete before any lane's store below — lockstep instruction stream)
  uint16_t* P = (uint16_t*)sc;
  long long pb = (long long)r * 1024;
  *(short8*)&P[pb + t0] = oh;
  *(short8*)&P[pb + 512 + t0] = ol;
}

// ---------------------------------------------------------------- host
extern "C" void kernel_launch(void* const* d_in, const int* in_sizes, int n_in,
                              void* d_out, int out_size, void* d_ws, size_t ws_size,
                              hipStream_t stream) {
  const float* h    = (const float*)d_in[0];
  const float* gt   = (const float*)d_in[1];
  const float* W_ih = (const float*)d_in[3];
  const float* W_hh = (const float*)d_in[4];
  const float* b_ih = (const float*)d_in[5];
  const float* b_hh = (const float*)d_in[6];
  const float* tp_W = (const float*)d_in[7];
  const float* tp_b = (const float*)d_in[8];
  const float* tQ_W = (const float*)d_in[9];
  const float* tQ_b = (const float*)d_in[10];
  const float* tK_W = (const float*)d_in[11];
  const float* tK_b = (const float*)d_in[12];
  const float* tV_W = (const float*)d_in[13];
  const float* tV_b = (const float*)d_in[14];
  const float* sQ_W = (const float*)d_in[15];
  const float* sQ_b = (const float*)d_in[16];
  const float* sK_W = (const float*)d_in[17];
  const float* sK_b = (const float*)d_in[18];
  const float* sV_W = (const float*)d_in[19];
  const float* sV_b = (const float*)d_in[20];
  const float* mlp_W= (const float*)d_in[21];
  const float* mlp_b= (const float*)d_in[22];
  const float* lin_W= (const float*)d_in[23];
  const float* lin_b= (const float*)d_in[24];
  (void)in_sizes; (void)n_in;

  char* wsb = (char*)d_ws;
  size_t off = 0;
  auto carve = [&](size_t bytes) -> void* {
    void* p = wsb + off;
    off += (bytes + 255) & ~(size_t)255;
    return p;
  };
  // Wreg union: GRU triple packs (41.9MB) in phase 1; phase-2 weight splits (30.9MB) after
  char* Wreg = (char*)carve(41877504);
  uint16_t* B0 = (uint16_t*)Wreg;                       // gate pack hi
  uint16_t* B1 = (uint16_t*)(Wreg + 13762560);          // gate pack mid
  uint16_t* B2 = (uint16_t*)(Wreg + 27525120);          // gate pack lo
  uint16_t* Bx = (uint16_t*)(Wreg + 41287680);          // x pack (3 planes x 196608B)
  uint16_t* tQ3 = (uint16_t*)(Wreg);                    // phase-2 overlay
  uint16_t* tK3 = (uint16_t*)(Wreg + 6291456);
  uint16_t* sQ3 = (uint16_t*)(Wreg + 12582912);
  uint16_t* mlp3= (uint16_t*)(Wreg + 18874368);
  uint16_t* sK3 = (uint16_t*)(Wreg + 25165824);
  uint16_t* tV2 = (uint16_t*)(Wreg + 25755648);
  uint16_t* sV2 = (uint16_t*)(Wreg + 29949952);
  uint16_t* lin2= (uint16_t*)(Wreg + 30343168);
  float* c6m    = (float*)carve(6240 * 4);
  float* Hf     = (float*)carve(32768LL * 1024 * 4);    // 128MB exact f32 H
  float* Xf     = (float*)carve(32768LL * 96 * 4);      // 12MB  exact f32 X
  uint16_t* Hr  = (uint16_t*)carve(2 * 64 * 3072 * 2);  // rolling h triple (ping-pong)
  uint16_t* Xr  = (uint16_t*)carve(2 * 64 * 288 * 2);   // rolling x triple
  uint16_t* Xm1 = (uint16_t*)carve(64 * 288 * 2);
  uint16_t* Hs  = (uint16_t*)carve(2048LL * 3072 * 2);  // 12.6MB chunk H triple
  uint16_t* Xs  = (uint16_t*)carve(2048LL * 288 * 2);   // 1.2MB chunk X triple
  uint16_t* Qc  = (uint16_t*)carve(2048LL * 3072 * 2);  // 12.6MB chunk Q triple
  uint16_t* Kc  = (uint16_t*)carve(2048LL * 3072 * 2);  // 12.6MB chunk K triple / MLP f32 temp
  uint16_t* Vc  = (uint16_t*)carve(4LL * 1024 * 1024 * 2); // 8MB chunk V^T pair [4][1024][1024]
  float* scr    = (float*)carve(2048LL * 512 * 4);      // 4MB chunk scores f32 (P pair overlays)
  size_t need = off;  // ~242 MB
  if (ws_size < need) {
    k_fill<<<dim3((out_size + 255) / 256), 256, 0, stream>>>((float*)d_out, out_size,
                                                             40000.0f + (float)(ws_size >> 20));
    return;
  }

  // ---- phase 1 prep
  k_pack<<<dim3(3360), 256, 0, stream>>>(W_hh, W_ih, tp_W, B0, B1, B2);
  k_packx<<<dim3(48), 256, 0, stream>>>(tp_W, Bx);
  k_c6<<<dim3(25), 256, 0, stream>>>(b_ih, b_hh, W_ih, tp_b, c6m);
  k_init<<<dim3(280), 256, 0, stream>>>(h, gt, Hf, Hr, Xf, Xr);
  k_xm1<<<dim3(24), 256, 0, stream>>>(h, gt, tp_W, tp_b, Xm1);

  // ---- phase 1: GRU scan (step p: gates -> h_{p+1}; x-update -> x_p)
  for (int p = 0; p < 512; p++) {
    const uint16_t* Xg = (p == 0) ? Xm1 : (Xr + ((p - 1) & 1) * 18432);
    k_gru<<<dim3(33), dim3(512), 0, stream>>>(B0, B1, B2, Bx, c6m, Hf, Hr, Xf, Xr, Xg,
                                              p, (p < 511) ? 1 : 0, (p >= 1) ? 1 : 0);
  }

  // ---- phase 2: 16 chunks x 2048 rows (4 batches each)
  for (int i = 0; i < 2; i++) {
    k_wsplit3<<<dim3(4096), 256, 0, stream>>>(tQ_W + (long long)i * 1048576, tQ3, 1024, 1024, 1024);
    k_wsplit3<<<dim3(4096), 256, 0, stream>>>(tK_W + (long long)i * 1048576, tK3, 1024, 1024, 1024);
    k_wsplit3<<<dim3(4096), 256, 0, stream>>>(sQ_W + (long long)i * 1048576, sQ3, 1024, 1024, 1024);
    k_wsplit3<<<dim3(4096), 256, 0, stream>>>(mlp_W + (long long)i * 1048576, mlp3, 1024, 1024, 1024);
    k_wsplit3<<<dim3(384), 256, 0, stream>>>(sK_W + (long long)i * 98304, sK3, 1024, 96, 1024);
    k_fsplit<<<dim3(4096), 256, 0, stream>>>(tV_W + (long long)i * 1048576, tV2, 1024, 1024, 1024);
    k_fsplit<<<dim3(384), 256, 0, stream>>>(sV_W + (long long)i * 98304, sV2, 1024, 96, 1024);

    // temporal attention (causal)
    for (int c = 0; c < 16; c++) {
      float* Hc = Hf + (long long)c * 2048 * 1024;
      k_split3<<<dim3(8192), 256, 0, stream>>>(Hc, Hs, 2097152, 1024);
      k_gemmX<0,1,1,0,0,0,0, 3,3,2><<<dim3(16, 8, 1), 256, 0, stream>>>(
          Hs, 3072, 0, 1024, tQ3, 3072, 0, 1024, nullptr, 0, 0, Qc, 3072, 0, 1024,
          tQ_b + i * 1024, 0.f, 32, 1024);
      k_gemmX<0,1,1,0,0,0,0, 3,3,2><<<dim3(16, 8, 1), 256, 0, stream>>>(
          Hs, 3072, 0, 1024, tK3, 3072, 0, 1024, nullptr, 0, 0, Kc, 3072, 0, 1024,
          tK_b + i * 1024, 0.f, 32, 1024);
      k_gemmX<0,0,2,0,0,0,1, 2,2,1><<<dim3(8, 16, 1), 256, 0, stream>>>(
          tV2, 2048, 0, 1024, Hs, 3072, 0, 1024, nullptr, 0, 0, Vc, 0, 0, 0,
          tV_b + i * 1024, 0.f, 32, 2048);
      k_gemmX<1,0,0,0,0,1,0, 3,3,2><<<dim3(4, 4, 4), 256, 0, stream>>>(
          Qc, 3072, 1572864, 1024, Kc, 3072, 1572864, 1024, scr, 512, 262144,
          nullptr, 0, 0, 0, nullptr, 0.03125f, 32, 512);
      k_softmax<<<dim3(512), 256, 0, stream>>>(scr, 1);
      k_gemmX<0,0,0,1,0,0,0, 2,2,1><<<dim3(4, 8, 4), 256, 0, stream>>>(
          (const uint16_t*)scr, 1024, 524288, 512, Vc, 1024, 1048576, 512,
          Hc, 1024, 524288, nullptr, 0, 0, 0, nullptr, 0.f, 16, 1024);
    }
    // spatial attention (K/V from X, no mask)
    for (int c = 0; c < 16; c++) {
      float* Hc = Hf + (long long)c * 2048 * 1024;
      k_split3<<<dim3(8192), 256, 0, stream>>>(Hc, Hs, 2097152, 1024);
      k_split3<<<dim3(768), 256, 0, stream>>>(Xf + (long long)c * 2048 * 96, Xs, 196608, 96);
      k_gemmX<0,1,1,0,0,0,0, 3,3,2><<<dim3(16, 8, 1), 256, 0, stream>>>(
          Hs, 3072, 0, 1024, sQ3, 3072, 0, 1024, nullptr, 0, 0, Qc, 3072, 0, 1024,
          sQ_b + i * 1024, 0.f, 32, 1024);
      k_gemmX<0,1,1,0,0,0,0, 3,3,2><<<dim3(16, 8, 1), 256, 0, stream>>>(
          Xs, 288, 0, 96, sK3, 288, 0, 96, nullptr, 0, 0, Kc, 3072, 0, 1024,
          sK_b + i * 1024, 0.f, 3, 1024);
      k_gemmX<0,0,2,0,0,0,1, 2,2,1><<<dim3(8, 16, 1), 256, 0, stream>>>(
          sV2, 192, 0, 96, Xs, 288, 0, 96, nullptr, 0, 0, Vc, 0, 0, 0,
          sV_b + i * 1024, 0.f, 3, 2048);
      k_gemmX<1,0,0,0,0,1,0, 3,3,2><<<dim3(4, 4, 4), 256, 0, stream>>>(
          Qc, 3072, 1572864, 1024, Kc, 3072, 1572864, 1024, scr, 512, 262144,
          nullptr, 0, 0, 0, nullptr, 0.03125f, 32, 512);
      k_softmax<<<dim3(512), 256, 0, stream>>>(scr, 0);
      k_gemmX<0,0,0,1,0,0,0, 2,2,1><<<dim3(4, 8, 4), 256, 0, stream>>>(
          (const uint16_t*)scr, 1024, 524288, 512, Vc, 1024, 1048576, 512,
          Hc, 1024, 524288, nullptr, 0, 0, 0, nullptr, 0.f, 16, 1024);
    }
    // MLP (leaky-relu), via f32 temp in Kc to avoid in-place hazard
    for (int c = 0; c < 16; c++) {
      float* Hc = Hf + (long long)c * 2048 * 1024;
      k_split3<<<dim3(8192), 256, 0, stream>>>(Hc, Hs, 2097152, 1024);
      k_gemmX<1,0,1,0,1,0,0, 3,3,2><<<dim3(16, 8, 1), 256, 0, stream>>>(
          Hs, 3072, 0, 1024, mlp3, 3072, 0, 1024, (float*)Kc, 1024, 0,
          nullptr, 0, 0, 0, mlp_b + i * 1024, 0.f, 32, 1024);
      k_cp4<<<dim3(2048), 256, 0, stream>>>((const float4*)Kc, (float4*)Hc, 524288);
    }
  }
  // head: out = H @ lin_W^T + lin_b (pair precision; direct path)
  k_fsplit<<<dim3(512), 256, 0, stream>>>(lin_W, lin2, 96, 1024, 128);
  for (int c = 0; c < 16; c++) {
    float* Hc = Hf + (long long)c * 2048 * 1024;
    k_split3<<<dim3(8192), 256, 0, stream>>>(Hc, Hs, 2097152, 1024);
    k_gemmX<1,0,1,0,0,0,0, 2,2,1><<<dim3(16, 1, 1), 256, 0, stream>>>(
        Hs, 3072, 0, 1024, lin2, 2048, 0, 1024, (float*)d_out + (long long)c * 2048 * 96, 96, 0,
        nullptr, 0, 0, 0, lin_b, 0.f, 32, 96);
  }
}

// Round 10
// 34369.952 us; speedup vs baseline: 1.7468x; 1.7468x over previous
//
#include <hip/hip_runtime.h>
#include <stdint.h>

// Decoder_71880572665909 : GRU scan (T=511) + 2 x (causal self-attn + cross-attn + MLP) + linear head
// B=64, S=512, HID=1024, POSE=96, L=2.
// Numerics: H,X carried exact f32 (511-step chains). Weight packs triple-bf16 (coherent-bias kill);
// activation operands pair-bf16 (random rounding, X3-class products). ws budget observed 236-300 MB
// (run-variable!); this build needs ~213 MB.

typedef __attribute__((ext_vector_type(8))) short short8;
typedef __attribute__((ext_vector_type(4))) float f32x4;

__device__ __forceinline__ uint16_t f2bf(float f) {
  uint32_t u = __float_as_uint(f);
  uint32_t r = u + 0x7FFFu + ((u >> 16) & 1u);
  return (uint16_t)(r >> 16);
}
__device__ __forceinline__ float bf2f(uint16_t h) {
  return __uint_as_float(((uint32_t)h) << 16);
}
__device__ __forceinline__ float sigm(float x) { return 1.f / (1.f + __expf(-x)); }
__device__ __forceinline__ float tanh_(float x) { return 2.f / (1.f + __expf(-2.f * x)) - 1.f; }
__device__ __forceinline__ short8 ld8(const uint16_t* p) { return *(const short8*)p; }

__device__ __forceinline__ void stage16(const void* g, void* lds_base_uniform) {
  __builtin_amdgcn_global_load_lds((const __attribute__((address_space(1))) void*)g,
                                   (__attribute__((address_space(3))) void*)lds_base_uniform, 16, 0, 0);
}
__device__ __forceinline__ void tri_store(uint16_t* p, long long o0, long long o1, long long o2, float v) {
  uint16_t hi = f2bf(v);
  float r = v - bf2f(hi);
  uint16_t mid = f2bf(r);
  p[o0] = hi; p[o1] = mid; p[o2] = f2bf(r - bf2f(mid));
}
__device__ __forceinline__ void pair_store(uint16_t* p, long long o0, long long o1, float v) {
  uint16_t hi = f2bf(v);
  p[o0] = hi; p[o1] = f2bf(v - bf2f(hi));
}

// ---------------------------------------------------------------- prep / utility kernels

__global__ __launch_bounds__(256) void k_fill(float* __restrict__ o, int n, float v) {
  int i = blockIdx.x * 256 + threadIdx.x;
  if (i < n) o[i] = v;
}

__global__ __launch_bounds__(256) void k_cp4(const float4* __restrict__ s, float4* __restrict__ d, int n4) {
  int i = blockIdx.x * 256 + threadIdx.x;
  if (i < n4) d[i] = s[i];
}

// f32 [rows][K] -> pair bf16 [rows][2K] (hi|lo)
__global__ __launch_bounds__(256) void k_split2(const float* __restrict__ s, uint16_t* __restrict__ d,
                                                int n, int K) {
  int id = blockIdx.x * 256 + threadIdx.x;
  if (id >= n) return;
  int row = id / K, k = id % K;
  long long b = (long long)row * 2 * K;
  pair_store(d, b + k, b + K + k, s[id]);
}

// f32 W [N][K] -> pair [Npad][2K]
__global__ __launch_bounds__(256) void k_fsplit(const float* __restrict__ s, uint16_t* __restrict__ d,
                                                int N, int K, int Npad) {
  int id = blockIdx.x * 256 + threadIdx.x;
  if (id >= Npad * K) return;
  int n = id / K, k = id % K;
  float w = (n < N) ? s[(long long)n * K + k] : 0.f;
  pair_store(d, (long long)n * 2 * K + k, (long long)n * 2 * K + K + k, w);
}

// f32 W [N][K] -> triple [Npad][3K]
__global__ __launch_bounds__(256) void k_wsplit3(const float* __restrict__ s, uint16_t* __restrict__ d,
                                                 int N, int K, int Npad) {
  int id = blockIdx.x * 256 + threadIdx.x;
  if (id >= Npad * K) return;
  int n = id / K, k = id % K;
  float w = (n < N) ? s[(long long)n * K + k] : 0.f;
  tri_store(d, (long long)n * 3 * K + k, (long long)n * 3 * K + K + k, (long long)n * 3 * K + 2 * K + k, w);
}

// x_{-1} = x0 - h0 @ tp_W^T - tp_b  (triple out; feeds step-0 gi)
__global__ __launch_bounds__(256) void k_xm1(const float* __restrict__ h, const float* __restrict__ gt,
                                             const float* __restrict__ tp_W, const float* __restrict__ tp_b,
                                             uint16_t* __restrict__ Xm1) {
  int id = blockIdx.x * 256 + threadIdx.x;
  if (id >= 64 * 96) return;
  int b = id / 96, c = id % 96;
  float s = gt[(long long)b * 512 * 96 + c] - tp_b[c];
  const float* hr = &h[(long long)b * 1024];
  const float* wr = &tp_W[(long long)c * 1024];
  for (int k = 0; k < 1024; k++) s -= hr[k] * wr[k];
  tri_store(Xm1, b * 288 + c, b * 288 + 96 + c, b * 288 + 192 + c, s);
}

// gates pack: K=1120 x N=6144 fragment order [384 tiles][35 ks][64][8], triple planes
__global__ __launch_bounds__(256) void k_pack(const float* __restrict__ W_hh, const float* __restrict__ W_ih,
                                              const float* __restrict__ tp_W,
                                              uint16_t* __restrict__ B0, uint16_t* __restrict__ B1,
                                              uint16_t* __restrict__ B2) {
  int id = blockIdx.x * 256 + threadIdx.x;
  if (id >= 384 * 35 * 64) return;
  int tile = id / 2240, rem = id % 2240;
  int ks = rem >> 6, l = rem & 63;
  int n = tile * 16 + (l & 15);
  int kb = ks * 32 + (l >> 4) * 8;
  short8 v0, v1, v2;
#pragma unroll
  for (int i = 0; i < 8; i++) {
    int k = kb + i;
    float m = 0.f;
    if (n < 3072) {
      m = (k < 1024) ? W_hh[(long long)n * 1024 + k] : 0.f;
    } else {
      int j = n - 3072;
      if (k < 1024) {
        float s = 0.f;
        for (int q = 0; q < 96; q++) s += tp_W[q * 1024 + k] * W_ih[(long long)j * 96 + q];
        m = s;
      } else {
        m = W_ih[(long long)j * 96 + (k - 1024)];
      }
    }
    uint16_t hi = f2bf(m);
    float r = m - bf2f(hi);
    uint16_t mid = f2bf(r);
    v0[i] = (short)hi; v1[i] = (short)mid; v2[i] = (short)f2bf(r - bf2f(mid));
  }
  *(short8*)&B0[(long long)id * 8] = v0;
  *(short8*)&B1[(long long)id * 8] = v1;
  *(short8*)&B2[(long long)id * 8] = v2;
}

// x-update pack: tp_W [6 tiles][32 ks][64][8], triple planes (plane stride 98304 u16)
__global__ __launch_bounds__(256) void k_packx(const float* __restrict__ tp_W, uint16_t* __restrict__ Bx) {
  int id = blockIdx.x * 256 + threadIdx.x;
  if (id >= 6 * 32 * 64) return;
  int tile = id / 2048, rem = id % 2048;
  int ks = rem >> 6, l = rem & 63;
  int c = tile * 16 + (l & 15);
  int lg = l >> 4;
  short8 v0, v1, v2;
#pragma unroll
  for (int i = 0; i < 8; i++) {
    int k = ks * 32 + lg * 8 + i;
    float w = tp_W[(long long)c * 1024 + k];
    uint16_t hi = f2bf(w);
    float r = w - bf2f(hi);
    uint16_t mid = f2bf(r);
    v0[i] = (short)hi; v1[i] = (short)mid; v2[i] = (short)f2bf(r - bf2f(mid));
  }
  *(short8*)&Bx[(long long)id * 8] = v0;
  *(short8*)&Bx[98304 + (long long)id * 8] = v1;
  *(short8*)&Bx[196608 + (long long)id * 8] = v2;
}

__global__ __launch_bounds__(256) void k_c6(const float* __restrict__ b_ih, const float* __restrict__ b_hh,
                                            const float* __restrict__ W_ih, const float* __restrict__ tp_b,
                                            float* __restrict__ c6m) {
  int n = blockIdx.x * 256 + threadIdx.x;
  if (n >= 6240) return;
  float m;
  if (n < 3072) { m = b_hh[n]; }
  else if (n < 6144) {
    int j = n - 3072;
    float s = 0.f;
    for (int q = 0; q < 96; q++) s += W_ih[(long long)j * 96 + q] * tp_b[q];
    m = b_ih[j] + s;
  } else { m = tp_b[n - 6144]; }
  c6m[n] = m;
}

__global__ __launch_bounds__(256) void k_init(const float* __restrict__ h, const float* __restrict__ gt,
                                              float* Hf, uint16_t* Hr, float* Xf, uint16_t* Xr) {
  int id = blockIdx.x * 256 + threadIdx.x;
  if (id < 65536) {
    int b = id >> 10, d = id & 1023;
    float v = h[id];
    Hf[((long long)b * 512) * 1024 + d] = v;
    tri_store(Hr, b * 3072 + d, b * 3072 + 1024 + d, b * 3072 + 2048 + d, v);
  } else {
    int r2 = id - 65536;
    if (r2 < 6144) {
      int b = r2 / 96, c = r2 % 96;
      float v = gt[(long long)b * 512 * 96 + c];
      Xf[((long long)b * 512) * 96 + c] = v;
      tri_store(Xr, b * 288 + c, b * 288 + 96 + c, b * 288 + 192 + c, v);
    }
  }
}

// ---------------------------------------------------------------- GRU step
// grid 66: blocks 0..63 gates (16 j-cols x 6 strips), blocks 64,65 x-update (48 cols each).
// Rolling triple buffers: Hcur [64][3072], Xg [64][288].
__global__ __launch_bounds__(512) void k_gru(const uint16_t* __restrict__ B0, const uint16_t* __restrict__ B1,
                                             const uint16_t* __restrict__ B2, const uint16_t* __restrict__ Bx,
                                             const float* __restrict__ c6,
                                             float* Hf, uint16_t* Hr, float* Xf, uint16_t* Xr,
                                             const uint16_t* __restrict__ Xg,
                                             int p, int do_g, int do_x) {
  int tid = threadIdx.x, w = tid >> 6, l = tid & 63, lr = l & 15, lg = l >> 4;
  int blk = blockIdx.x;
  const uint16_t* Hcur = Hr + (p & 1) * 196608;
  uint16_t* Hnxt = Hr + ((p + 1) & 1) * 196608;
  uint16_t* Xw = Xr + (p & 1) * 18432;
  __shared__ float lds[4 * 6144];

  if (blk >= 64) {  // x-update: x_p = x_{p-1} + h_p @ tpW^T + tp_b ; X6 precision
    if (!do_x) return;
    int xb = blk - 64;
    if (w < 6) {
      int tl = xb * 3 + (w >> 1);
      int kh = w & 1;
      f32x4 ac[4] = {};
      for (int ks = kh * 16; ks < kh * 16 + 16; ks++) {
        short8 a0[4], a1[4], a2[4];
        int k0 = ks * 32 + lg * 8;
#pragma unroll
        for (int rt = 0; rt < 4; rt++) {
          int hb = (rt * 16 + lr) * 3072;
          a0[rt] = ld8(&Hcur[hb + k0]);
          a1[rt] = ld8(&Hcur[hb + 1024 + k0]);
          a2[rt] = ld8(&Hcur[hb + 2048 + k0]);
        }
        long long bo = (((long long)tl * 32 + ks) * 64 + l) * 8;
        short8 b0 = ld8(&Bx[bo]);
        short8 b1 = ld8(&Bx[98304 + bo]);
        short8 b2 = ld8(&Bx[196608 + bo]);
#pragma unroll
        for (int rt = 0; rt < 4; rt++) {
          ac[rt] = __builtin_amdgcn_mfma_f32_16x16x32_bf16(a0[rt], b0, ac[rt], 0, 0, 0);
          ac[rt] = __builtin_amdgcn_mfma_f32_16x16x32_bf16(a0[rt], b1, ac[rt], 0, 0, 0);
          ac[rt] = __builtin_amdgcn_mfma_f32_16x16x32_bf16(a1[rt], b0, ac[rt], 0, 0, 0);
          ac[rt] = __builtin_amdgcn_mfma_f32_16x16x32_bf16(a1[rt], b1, ac[rt], 0, 0, 0);
          ac[rt] = __builtin_amdgcn_mfma_f32_16x16x32_bf16(a0[rt], b2, ac[rt], 0, 0, 0);
          ac[rt] = __builtin_amdgcn_mfma_f32_16x16x32_bf16(a2[rt], b0, ac[rt], 0, 0, 0);
        }
      }
#pragma unroll
      for (int rt = 0; rt < 4; rt++)
#pragma unroll
        for (int rg = 0; rg < 4; rg++)
          lds[w * 1024 + (rt * 16 + 4 * lg + rg) * 16 + lr] = ac[rt][rg];
    }
    __syncthreads();
    for (int idx = tid; idx < 3072; idx += 512) {
      int ti = idx >> 10, rem = idx & 1023;
      int row = rem >> 4, cl = rem & 15;
      float v = lds[(2 * ti) * 1024 + row * 16 + cl] + lds[(2 * ti + 1) * 1024 + row * 16 + cl];
      int c = (xb * 3 + ti) * 16 + cl;
      float xold = Xf[((long long)row * 512 + p - 1) * 96 + c];
      float xv = v + c6[6144 + c] + xold;
      Xf[((long long)row * 512 + p) * 96 + c] = xv;
      tri_store(Xw, row * 288 + c, row * 288 + 96 + c, row * 288 + 192 + c, xv);
    }
    return;
  }

  if (!do_g) return;
  // gates: j in [blk*16, +16); tiles s*64+blk for s=0..5. 8 waves split K(35 ks).
  int ks0 = (w * 35) >> 3, ks1 = ((w + 1) * 35) >> 3;
  f32x4 acc[6][4] = {};
  for (int ks = ks0; ks < ks1; ks++) {
    short8 a0[4], a1[4];
    if (ks < 32) {
      int k0 = ks * 32 + lg * 8;
#pragma unroll
      for (int rt = 0; rt < 4; rt++) {
        int hb = (rt * 16 + lr) * 3072;
        a0[rt] = ld8(&Hcur[hb + k0]);
        a1[rt] = ld8(&Hcur[hb + 1024 + k0]);
      }
    } else {
      int k0 = (ks - 32) * 32 + lg * 8;
#pragma unroll
      for (int rt = 0; rt < 4; rt++) {
        int xb2 = (rt * 16 + lr) * 288;
        a0[rt] = ld8(&Xg[xb2 + k0]);
        a1[rt] = ld8(&Xg[xb2 + 96 + k0]);
      }
    }
#pragma unroll
    for (int t = 0; t < 6; t++) {
      long long bo = (((long long)(t * 64 + blk)) * 35 + ks) * 64 * 8 + (long long)l * 8;
      short8 b0 = ld8(&B0[bo]);
      short8 b1 = ld8(&B1[bo]);
      short8 b2 = ld8(&B2[bo]);
#pragma unroll
      for (int rt = 0; rt < 4; rt++) {
        acc[t][rt] = __builtin_amdgcn_mfma_f32_16x16x32_bf16(a0[rt], b0, acc[t][rt], 0, 0, 0);
        acc[t][rt] = __builtin_amdgcn_mfma_f32_16x16x32_bf16(a0[rt], b1, acc[t][rt], 0, 0, 0);
        acc[t][rt] = __builtin_amdgcn_mfma_f32_16x16x32_bf16(a1[rt], b0, acc[t][rt], 0, 0, 0);
        acc[t][rt] = __builtin_amdgcn_mfma_f32_16x16x32_bf16(a0[rt], b2, acc[t][rt], 0, 0, 0);
      }
    }
  }
  int slab = w & 3;
  if (w < 4) {
#pragma unroll
    for (int t = 0; t < 6; t++)
#pragma unroll
      for (int rt = 0; rt < 4; rt++)
#pragma unroll
        for (int rg = 0; rg < 4; rg++)
          lds[slab * 6144 + (rt * 16 + 4 * lg + rg) * 96 + t * 16 + lr] = acc[t][rt][rg];
  }
  __syncthreads();
  if (w >= 4) {
#pragma unroll
    for (int t = 0; t < 6; t++)
#pragma unroll
      for (int rt = 0; rt < 4; rt++)
#pragma unroll
        for (int rg = 0; rg < 4; rg++)
          lds[slab * 6144 + (rt * 16 + 4 * lg + rg) * 96 + t * 16 + lr] += acc[t][rt][rg];
  }
  __syncthreads();
  for (int idx = tid; idx < 6144; idx += 512)
    lds[idx] = lds[idx] + lds[6144 + idx] + lds[12288 + idx] + lds[18432 + idx];
  __syncthreads();
  for (int item = tid; item < 1024; item += 512) {
    int b = item >> 4, jj = item & 15;
    int j = blk * 16 + jj;
    const float* row = &lds[b * 96];
    float hr = row[jj]       + c6[j];
    float hz = row[16 + jj]  + c6[1024 + j];
    float hnn = row[32 + jj] + c6[2048 + j];
    float ir = row[48 + jj]  + c6[3072 + j];
    float iz = row[64 + jj]  + c6[4096 + j];
    float inn = row[80 + jj] + c6[5120 + j];
    float hp = Hf[((long long)b * 512 + p) * 1024 + j];
    float r = sigm(ir + hr), z = sigm(iz + hz);
    float nn = tanh_(inn + r * hnn);
    float hv = (1.f - z) * nn + z * hp;
    Hf[((long long)b * 512 + p + 1) * 1024 + j] = hv;
    tri_store(Hnxt, b * 3072 + j, b * 3072 + 1024 + j, b * 3072 + 2048 + j, hv);
  }
}

// ---------------------------------------------------------------- generic multi-word GEMM
// A row-major [M][lda], words at w*koffA. B = B^T row-major [N][ldb], words at w*koffB.
// Accumulates all products a_i * b_j with i+j <= CUT.
template <int WF32, int WPAIR, int BIAS, int RESIDF, int LEAKY, int SCALE, int VLAY,
          int AW, int BW, int CUT>
__global__ __launch_bounds__(256) void k_gemmX(const uint16_t* __restrict__ A, int lda, long long bsA, int koffA,
                                               const uint16_t* __restrict__ B, int ldb, long long bsB, int koffB,
                                               float* __restrict__ C, int ldc, long long bsC,
                                               uint16_t* __restrict__ Cb, int ldcb, long long bsCb, int pairoff,
                                               const float* __restrict__ bias, long long bsBias,
                                               float scale, int nk, int Nvalid) {
  int tid = threadIdx.x, w = tid >> 6, l = tid & 63, lr = l & 15, lg = l >> 4;
  long long bz = blockIdx.z;
  int brow = blockIdx.x * 128, bcol = blockIdx.y * 128;
  const uint16_t* Ab = A + bz * bsA;
  const uint16_t* Bb = B + bz * bsB;
  const float* biasz = bias ? bias + bz * bsBias : bias;
  __shared__ uint16_t sm[(AW + BW) * 4096];
  char* L = (char*)sm;
  f32x4 acc[4][4] = {};
  int wr = (w >> 1) * 64, wc = (w & 1) * 64;
  int srow = tid >> 2, skoff = (tid & 3) * 8;
  for (int ks = 0; ks < nk; ks++) {
    __syncthreads();
    int k0 = ks * 32 + skoff;
#pragma unroll
    for (int aw = 0; aw < AW; aw++) {
      stage16(Ab + (long long)(brow + srow) * lda + aw * koffA + k0,      L + aw * 8192 + w * 1024);
      stage16(Ab + (long long)(brow + 64 + srow) * lda + aw * koffA + k0, L + aw * 8192 + 4096 + w * 1024);
    }
#pragma unroll
    for (int bw = 0; bw < BW; bw++) {
      stage16(Bb + (long long)(bcol + srow) * ldb + bw * koffB + k0,      L + (AW + bw) * 8192 + w * 1024);
      stage16(Bb + (long long)(bcol + 64 + srow) * ldb + bw * koffB + k0, L + (AW + bw) * 8192 + 4096 + w * 1024);
    }
    __syncthreads();
    short8 af[AW][4], bf[BW][4];
#pragma unroll
    for (int aw = 0; aw < AW; aw++)
#pragma unroll
      for (int mi = 0; mi < 4; mi++)
        af[aw][mi] = *(short8*)(L + aw * 8192 + ((wr + mi * 16 + lr) * 32 + lg * 8) * 2);
#pragma unroll
    for (int bw = 0; bw < BW; bw++)
#pragma unroll
      for (int ni = 0; ni < 4; ni++)
        bf[bw][ni] = *(short8*)(L + (AW + bw) * 8192 + ((wc + ni * 16 + lr) * 32 + lg * 8) * 2);
#pragma unroll
    for (int mi = 0; mi < 4; mi++)
#pragma unroll
      for (int ni = 0; ni < 4; ni++)
#pragma unroll
        for (int iw = 0; iw < AW; iw++)
#pragma unroll
          for (int jw = 0; jw < BW; jw++)
            if (iw + jw <= CUT)
              acc[mi][ni] = __builtin_amdgcn_mfma_f32_16x16x32_bf16(af[iw][mi], bf[jw][ni], acc[mi][ni], 0, 0, 0);
  }
#pragma unroll
  for (int mi = 0; mi < 4; mi++) {
#pragma unroll
    for (int ni = 0; ni < 4; ni++) {
      int row0 = brow + wr + mi * 16 + 4 * lg;
      int col = bcol + wc + ni * 16 + lr;
      if (col < Nvalid) {
#pragma unroll
        for (int rg = 0; rg < 4; rg++) {
          float v = acc[mi][ni][rg];
          if (SCALE) v *= scale;
          if (BIAS == 1) v += biasz[col];
          if (BIAS == 2) v += biasz[row0 + rg];
          if (RESIDF) {
            long long ci = bz * bsC + (long long)(row0 + rg) * ldc + col;
            v += C[ci];
            C[ci] = v;
          }
          if (LEAKY) v = (v > 0.f) ? v : 0.01f * v;
          if (WF32) C[bz * bsC + (long long)(row0 + rg) * ldc + col] = v;
          if (WPAIR) {
            long long cbi = bz * bsCb + (long long)(row0 + rg) * ldcb + col;
            pair_store(Cb, cbi, cbi + pairoff, v);
          }
          if (VLAY) {  // V^T pair layout per 512-batch: [bz2][d 1024][hi 512 | lo 512]
            int bz2 = col >> 9, t = col & 511;
            long long vi = (long long)bz2 * 1048576 + (long long)(row0 + rg) * 1024 + t;
            pair_store(Cb, vi, vi + 512, v);
          }
        }
      }
    }
  }
}

// ---------------------------------------------------------------- softmax (rows of 512), P pair overlays scr
__global__ __launch_bounds__(256) void k_softmax(float* __restrict__ sc, int causal) {
  int r = blockIdx.x * 4 + (threadIdx.x >> 6);
  int l = threadIdx.x & 63;
  int s = r & 511;
  long long base = (long long)r * 512;
  int t0 = l * 8;
  float4 p0 = *(const float4*)&sc[base + t0];
  float4 p1 = *(const float4*)&sc[base + t0 + 4];
  float v[8] = {p0.x, p0.y, p0.z, p0.w, p1.x, p1.y, p1.z, p1.w};
  float m = -3.0e38f;
#pragma unroll
  for (int i = 0; i < 8; i++) {
    bool ok = (!causal) || (t0 + i <= s);
    if (ok) m = fmaxf(m, v[i]);
  }
#pragma unroll
  for (int o = 32; o > 0; o >>= 1) m = fmaxf(m, __shfl_xor(m, o));
  float e[8];
  float sum = 0.f;
#pragma unroll
  for (int i = 0; i < 8; i++) {
    bool ok = (!causal) || (t0 + i <= s);
    e[i] = ok ? __expf(v[i] - m) : 0.f;
    sum += e[i];
  }
#pragma unroll
  for (int o = 32; o > 0; o >>= 1) sum += __shfl_xor(sum, o);
  float inv = 1.f / sum;
  short8 oh, ol;
#pragma unroll
  for (int i = 0; i < 8; i++) {
    float p = e[i] * inv;
    uint16_t hi = f2bf(p);
    oh[i] = hi; ol[i] = (short)f2bf(p - bf2f(hi));
  }
  uint16_t* P = (uint16_t*)sc;   // single wave owns the row: loads done before stores
  long long pb = (long long)r * 1024;
  *(short8*)&P[pb + t0] = oh;
  *(short8*)&P[pb + 512 + t0] = ol;
}

// ---------------------------------------------------------------- host
extern "C" void kernel_launch(void* const* d_in, const int* in_sizes, int n_in,
                              void* d_out, int out_size, void* d_ws, size_t ws_size,
                              hipStream_t stream) {
  const float* h    = (const float*)d_in[0];
  const float* gt   = (const float*)d_in[1];
  const float* W_ih = (const float*)d_in[3];
  const float* W_hh = (const float*)d_in[4];
  const float* b_ih = (const float*)d_in[5];
  const float* b_hh = (const float*)d_in[6];
  const float* tp_W = (const float*)d_in[7];
  const float* tp_b = (const float*)d_in[8];
  const float* tQ_W = (const float*)d_in[9];
  const float* tQ_b = (const float*)d_in[10];
  const float* tK_W = (const float*)d_in[11];
  const float* tK_b = (const float*)d_in[12];
  const float* tV_W = (const float*)d_in[13];
  const float* tV_b = (const float*)d_in[14];
  const float* sQ_W = (const float*)d_in[15];
  const float* sQ_b = (const float*)d_in[16];
  const float* sK_W = (const float*)d_in[17];
  const float* sK_b = (const float*)d_in[18];
  const float* sV_W = (const float*)d_in[19];
  const float* sV_b = (const float*)d_in[20];
  const float* mlp_W= (const float*)d_in[21];
  const float* mlp_b= (const float*)d_in[22];
  const float* lin_W= (const float*)d_in[23];
  const float* lin_b= (const float*)d_in[24];
  (void)in_sizes; (void)n_in;

  char* wsb = (char*)d_ws;
  size_t off = 0;
  auto carve = [&](size_t bytes) -> void* {
    void* p = wsb + off;
    off += (bytes + 255) & ~(size_t)255;
    return p;
  };
  // Wreg: GRU packs (41.9MB, phase 1) / phase-2 weights (29.5MB) + scr (4MB) + Xs (0.75MB)
  char* Wreg = (char*)carve(41877504);
  uint16_t* B0 = (uint16_t*)Wreg;
  uint16_t* B1 = (uint16_t*)(Wreg + 13762560);
  uint16_t* B2 = (uint16_t*)(Wreg + 27525120);
  uint16_t* Bx = (uint16_t*)(Wreg + 41287680);
  uint16_t* tQ3 = (uint16_t*)(Wreg);                    // triple; tK3 adjacent at +3145728 u16
  uint16_t* sQ3 = (uint16_t*)(Wreg + 12582912);
  uint16_t* mlp3= (uint16_t*)(Wreg + 18874368);
  uint16_t* sK3 = (uint16_t*)(Wreg + 25165824);
  uint16_t* tV2 = (uint16_t*)(Wreg + 25755648);
  uint16_t* sV2 = (uint16_t*)(Wreg + 29949952);
  uint16_t* lin2= (uint16_t*)(Wreg + 30343168);
  float* scr    = (float*)(Wreg + 30867456);            // 4 MB chunk scores; P pair overlays
  uint16_t* Xs  = (uint16_t*)(Wreg + 35061760);         // 0.75 MB chunk X pair
  float* c6m    = (float*)carve(6240 * 4);
  float* Hf     = (float*)carve(32768LL * 1024 * 4);    // 128MB exact f32 H
  float* Xf     = (float*)carve(32768LL * 96 * 4);      // 12MB  exact f32 X
  uint16_t* Hr  = (uint16_t*)carve(2 * 64 * 3072 * 2);  // rolling h triple (ping-pong)
  uint16_t* Xr  = (uint16_t*)carve(2 * 64 * 288 * 2);   // rolling x triple
  uint16_t* Xm1 = (uint16_t*)carve(64 * 288 * 2);
  float* bias2  = (float*)carve(2048 * 4);              // merged tQ_b|tK_b
  uint16_t* Hs  = (uint16_t*)carve(2048LL * 2048 * 2);  // 8MB chunk H pair
  uint16_t* Qc  = (uint16_t*)carve(2048LL * 2048 * 2);  // 8MB chunk Q pair (Kc adjacent)
  uint16_t* Kc  = (uint16_t*)carve(2048LL * 2048 * 2);  // 8MB chunk K pair
  uint16_t* Vc  = (uint16_t*)carve(4LL * 1024 * 1024 * 2); // 8MB chunk V^T pair [4][1024][1024]
  size_t need = off;  // ~213 MB
  if (ws_size < need) {
    k_fill<<<dim3((out_size + 255) / 256), 256, 0, stream>>>((float*)d_out, out_size,
                                                             50000.0f + (float)(ws_size >> 20));
    return;
  }

  // ---- phase 1 prep
  k_pack<<<dim3(3360), 256, 0, stream>>>(W_hh, W_ih, tp_W, B0, B1, B2);
  k_packx<<<dim3(48), 256, 0, stream>>>(tp_W, Bx);
  k_c6<<<dim3(25), 256, 0, stream>>>(b_ih, b_hh, W_ih, tp_b, c6m);
  k_init<<<dim3(280), 256, 0, stream>>>(h, gt, Hf, Hr, Xf, Xr);
  k_xm1<<<dim3(24), 256, 0, stream>>>(h, gt, tp_W, tp_b, Xm1);

  // ---- phase 1: GRU scan (step p: gates -> h_{p+1}; x-update -> x_p)
  for (int p = 0; p < 512; p++) {
    const uint16_t* Xg = (p == 0) ? Xm1 : (Xr + ((p - 1) & 1) * 18432);
    k_gru<<<dim3(66), dim3(512), 0, stream>>>(B0, B1, B2, Bx, c6m, Hf, Hr, Xf, Xr, Xg,
                                              p, (p < 511) ? 1 : 0, (p >= 1) ? 1 : 0);
  }

  // ---- phase 2: 16 chunks x 2048 rows (4 batches each)
  for (int i = 0; i < 2; i++) {
    k_wsplit3<<<dim3(4096), 256, 0, stream>>>(tQ_W + (long long)i * 1048576, tQ3, 1024, 1024, 1024);
    k_wsplit3<<<dim3(4096), 256, 0, stream>>>(tK_W + (long long)i * 1048576, tQ3 + 3145728, 1024, 1024, 1024);
    k_wsplit3<<<dim3(4096), 256, 0, stream>>>(sQ_W + (long long)i * 1048576, sQ3, 1024, 1024, 1024);
    k_wsplit3<<<dim3(4096), 256, 0, stream>>>(mlp_W + (long long)i * 1048576, mlp3, 1024, 1024, 1024);
    k_wsplit3<<<dim3(384), 256, 0, stream>>>(sK_W + (long long)i * 98304, sK3, 1024, 96, 1024);
    k_fsplit<<<dim3(4096), 256, 0, stream>>>(tV_W + (long long)i * 1048576, tV2, 1024, 1024, 1024);
    k_fsplit<<<dim3(384), 256, 0, stream>>>(sV_W + (long long)i * 98304, sV2, 1024, 96, 1024);
    if (i == 1) k_fsplit<<<dim3(512), 256, 0, stream>>>(lin_W, lin2, 96, 1024, 128);
    k_cp4<<<dim3(1), 256, 0, stream>>>((const float4*)(tQ_b + i * 1024), (float4*)bias2, 256);
    k_cp4<<<dim3(1), 256, 0, stream>>>((const float4*)(tK_b + i * 1024), (float4*)(bias2 + 1024), 256);

    for (int c = 0; c < 16; c++) {
      float* Hc = Hf + (long long)c * 2048 * 1024;
      k_split2<<<dim3(8192), 256, 0, stream>>>(Hc, Hs, 2097152, 1024);
      // --- temporal (causal) ---
      k_gemmX<0,1,1,0,0,0,0, 2,3,2><<<dim3(16, 8, 2), 256, 0, stream>>>(
          Hs, 2048, 0, 1024, tQ3, 3072, 3145728, 1024, nullptr, 0, 0,
          Qc, 2048, 4194304, 1024, bias2, 1024, 0.f, 32, 1024);
      k_gemmX<0,0,2,0,0,0,1, 2,2,1><<<dim3(8, 16, 1), 256, 0, stream>>>(
          tV2, 2048, 0, 1024, Hs, 2048, 0, 1024, nullptr, 0, 0, Vc, 0, 0, 0,
          tV_b + i * 1024, 0, 0.f, 32, 2048);
      k_gemmX<1,0,0,0,0,1,0, 2,2,1><<<dim3(4, 4, 4), 256, 0, stream>>>(
          Qc, 2048, 1048576, 1024, Kc, 2048, 1048576, 1024, scr, 512, 262144,
          nullptr, 0, 0, 0, nullptr, 0, 0.03125f, 32, 512);
      k_softmax<<<dim3(512), 256, 0, stream>>>(scr, 1);
      k_gemmX<0,1,0,1,0,0,0, 2,2,1><<<dim3(4, 8, 4), 256, 0, stream>>>(
          (const uint16_t*)scr, 1024, 524288, 512, Vc, 1024, 1048576, 512,
          Hc, 1024, 524288, Hs, 2048, 1048576, 1024, nullptr, 0, 0.f, 16, 1024);
      // --- spatial (K/V from X) ---
      k_split2<<<dim3(768), 256, 0, stream>>>(Xf + (long long)c * 2048 * 96, Xs, 196608, 96);
      k_gemmX<0,1,1,0,0,0,0, 2,3,2><<<dim3(16, 8, 1), 256, 0, stream>>>(
          Hs, 2048, 0, 1024, sQ3, 3072, 0, 1024, nullptr, 0, 0,
          Qc, 2048, 0, 1024, sQ_b + i * 1024, 0, 0.f, 32, 1024);
      k_gemmX<0,1,1,0,0,0,0, 2,3,2><<<dim3(16, 8, 1), 256, 0, stream>>>(
          Xs, 192, 0, 96, sK3, 288, 0, 96, nullptr, 0, 0,
          Kc, 2048, 0, 1024, sK_b + i * 1024, 0, 0.f, 3, 1024);
      k_gemmX<0,0,2,0,0,0,1, 2,2,1><<<dim3(8, 16, 1), 256, 0, stream>>>(
          sV2, 192, 0, 96, Xs, 192, 0, 96, nullptr, 0, 0, Vc, 0, 0, 0,
          sV_b + i * 1024, 0, 0.f, 3, 2048);
      k_gemmX<1,0,0,0,0,1,0, 2,2,1><<<dim3(4, 4, 4), 256, 0, stream>>>(
          Qc, 2048, 1048576, 1024, Kc, 2048, 1048576, 1024, scr, 512, 262144,
          nullptr, 0, 0, 0, nullptr, 0, 0.03125f, 32, 512);
      k_softmax<<<dim3(512), 256, 0, stream>>>(scr, 0);
      k_gemmX<0,1,0,1,0,0,0, 2,2,1><<<dim3(4, 8, 4), 256, 0, stream>>>(
          (const uint16_t*)scr, 1024, 524288, 512, Vc, 1024, 1048576, 512,
          Hc, 1024, 524288, Hs, 2048, 1048576, 1024, nullptr, 0, 0.f, 16, 1024);
      // --- MLP: reads Hs, writes Hf (f32) + Qc (pair; head input) — no alias with Hs ---
      k_gemmX<1,1,1,0,1,0,0, 2,3,2><<<dim3(16, 8, 1), 256, 0, stream>>>(
          Hs, 2048, 0, 1024, mlp3, 3072, 0, 1024, Hc, 1024, 0,
          Qc, 2048, 0, 1024, mlp_b + i * 1024, 0, 0.f, 32, 1024);
      // --- head (layer 1): reads MLP pair output from Qc ---
      if (i == 1) {
        k_gemmX<1,0,1,0,0,0,0, 2,2,1><<<dim3(16, 1, 1), 256, 0, stream>>>(
            Qc, 2048, 0, 1024, lin2, 2048, 0, 1024,
            (float*)d_out + (long long)c * 2048 * 96, 96, 0,
            nullptr, 0, 0, 0, lin_b, 0, 0.f, 32, 96);
      }
    }
  }
}